// Round 3
// baseline (279.335 us; speedup 1.0000x reference)
//
#include <hip/hip_runtime.h>
#include <hip/hip_bf16.h>

// ---------------------------------------------------------------------------
// TT-linear, rank-64 factorized:
//   W = A4(4096x64) . B4(64x4096)  =>  out = (x_pad @ A4) @ B4 + bias
//   S1/S2 : core chains -> A4t (64x4096 bf16), B4t (4096x64 bf16)
//   GEMM1 : zc[8192x512] = split-8-K partials of x @ A4        (reads 131 MB)
//   R     : zb[8192x64]  = sum of the 8 partials, bf16
//   GEMM2 : out = zb @ B4t^T + bias, K=64                      (writes 134 MB)
// ---------------------------------------------------------------------------

typedef __attribute__((ext_vector_type(8))) short short8;
typedef __attribute__((ext_vector_type(4))) float f32x4;

__device__ __forceinline__ short f2bf(float f) {
    union { float f; unsigned u; } c; c.f = f;
    unsigned u = c.u;
    unsigned r = (u + 0x7fffu + ((u >> 16) & 1u)) >> 16;  // RNE
    return (short)r;
}

__device__ __forceinline__ float bf2f(short s) {
    union { float f; unsigned u; } c;
    c.u = ((unsigned)(unsigned short)s) << 16;
    return c.f;
}

// ---------------- S1: small chain steps (2 blocks, LDS-staged) --------------
// block 0: A2 = c0*c1 (64x64, LDS) ; A3 = A2*c2 (512x64, global)
// block 1: B6 = c6*c7 (64x64, LDS) ; B5 = B6*c5 (64x512, global)
__global__ __launch_bounds__(1024) void tt_chain_small(
    const float* __restrict__ c0, const float* __restrict__ c1,
    const float* __restrict__ c2, const float* __restrict__ c7,
    const float* __restrict__ c6, const float* __restrict__ c5,
    float* __restrict__ A3, float* __restrict__ B5) {
    __shared__ float T[4096];
    const int t = threadIdx.x;
    if (blockIdx.x == 0) {
        for (int o = t; o < 4096; o += 1024) {
            int row = o >> 6, s = o & 63, i = row >> 3, d = row & 7;
            float acc = 0.f;
            for (int r = 0; r < 64; ++r)
                acc += c0[i * 64 + r] * c1[(r * 8 + d) * 64 + s];
            T[row * 64 + s] = acc;
        }
        __syncthreads();
        for (int o = t; o < 32768; o += 1024) {
            int row = o >> 6, s = o & 63, i = row >> 3, d = row & 7;
            float acc = 0.f;
            for (int r = 0; r < 64; ++r)
                acc += T[i * 64 + r] * c2[(r * 8 + d) * 64 + s];
            A3[row * 64 + s] = acc;
        }
    } else {
        for (int o = t; o < 4096; o += 1024) {
            int rd = o >> 3, j = o & 7, r = rd >> 3, d = rd & 7;
            float acc = 0.f;
            for (int q = 0; q < 64; ++q)
                acc += c6[(r * 8 + d) * 64 + q] * c7[q * 8 + j];
            T[r * 64 + d * 8 + j] = acc;
        }
        __syncthreads();
        // B5[r][d*64+j2] = sum_q c5[(r*8+d)*64+q] * B6[q][j2]
        for (int o = t; o < 32768; o += 1024) {
            int r = o >> 9, dj = o & 511, d = dj >> 6, j2 = dj & 63;
            float acc = 0.f;
            for (int q = 0; q < 64; ++q)
                acc += c5[(r * 8 + d) * 64 + q] * T[q * 64 + j2];
            B5[r * 512 + d * 64 + j2] = acc;
        }
    }
}

// ---------------- S2: wide final steps, bf16 transposed outputs -------------
// blocks [0,1024):   A4t[s][row] = f2bf( sum_r A3[row>>3][r]*c3[(r*8+d)*64+s] )
// blocks [1024,1536): B4t[(d*512+j)][r] = f2bf( sum_q c4[(r*8+d)*64+q]*B5[q][j] )
__global__ __launch_bounds__(256) void tt_chain_wide(
    const float* __restrict__ A3, const float* __restrict__ c3,
    const float* __restrict__ B5, const float* __restrict__ c4,
    short* __restrict__ A4t, short* __restrict__ B4t) {
    const int bid = blockIdx.x, t = threadIdx.x;
    if (bid < 1024) {
        const int row = (bid << 2) | (t >> 6);
        const int s = t & 63;
        const int i = row >> 3, d = row & 7;
        float acc = 0.f;
        for (int r = 0; r < 64; ++r)
            acc += A3[i * 64 + r] * c3[(r * 8 + d) * 64 + s];
        A4t[s * 4096 + row] = f2bf(acc);
    } else {
        const int rd = bid - 1024;
        const int r = rd >> 3, d = rd & 7;
        for (int j = t; j < 512; j += 256) {
            float acc = 0.f;
            for (int q = 0; q < 64; ++q)
                acc += c4[(r * 8 + d) * 64 + q] * B5[q * 512 + j];
            B4t[(d * 512 + j) * 64 + r] = f2bf(acc);
        }
    }
}

// ---------------- GEMM1: zc[b][ks*64+r] = sum_{k in split ks} x[b][k]A4[k][r]
// grid = 128 mblocks x 8 ksplits, 256 threads (4 waves x 16 rows each).
__global__ __launch_bounds__(256) void gemm1_kernel(
    const float* __restrict__ x, const short* __restrict__ A4t,
    short* __restrict__ zc) {
    const int tid = threadIdx.x, wave = tid >> 6, lane = tid & 63;
    const int mb = blockIdx.x >> 3, ks = blockIdx.x & 7;
    const int m0 = mb * 64 + wave * 16;
    const int kt0 = (ks * 125) >> 3, kt1 = ((ks + 1) * 125) >> 3;
    const int r16 = lane & 15, kq = (lane >> 4) << 3;
    const float* xp = x + (long)(m0 + r16) * 4000 + kq;

    f32x4 acc[4] = {};
    for (int t = kt0; t < kt1; ++t) {
        const int k0 = t << 5;
        f32x4 u0 = *(const f32x4*)(xp + k0);
        f32x4 u1 = *(const f32x4*)(xp + k0 + 4);
        short8 a;
        a[0] = f2bf(u0[0]); a[1] = f2bf(u0[1]);
        a[2] = f2bf(u0[2]); a[3] = f2bf(u0[3]);
        a[4] = f2bf(u1[0]); a[5] = f2bf(u1[1]);
        a[6] = f2bf(u1[2]); a[7] = f2bf(u1[3]);
#pragma unroll
        for (int f = 0; f < 4; ++f) {
            short8 b = *(const short8*)(A4t + (f * 16 + r16) * 4096 + k0 + kq);
            acc[f] = __builtin_amdgcn_mfma_f32_16x16x32_bf16(a, b, acc[f], 0, 0, 0);
        }
    }
    const int zr = m0 + ((lane >> 4) << 2);
#pragma unroll
    for (int f = 0; f < 4; ++f) {
        const int c = ks * 64 + f * 16 + r16;
#pragma unroll
        for (int u = 0; u < 4; ++u)
            zc[(zr + u) * 512 + c] = f2bf(acc[f][u]);
    }
}

// ---------------- R: zb[b][r] = f2bf( sum_{s<8} zc[b][s*64+r] ) -------------
__global__ __launch_bounds__(256) void reduce_zc(const short* __restrict__ zc,
                                                 short* __restrict__ zb) {
    const int t = blockIdx.x * 256 + threadIdx.x;  // 65536 threads
    const int b = t >> 3, g = t & 7;
    const short* p = zc + b * 512 + g * 8;
    float acc[8] = {};
#pragma unroll
    for (int s = 0; s < 8; ++s) {
        short8 v = *(const short8*)(p + s * 64);
#pragma unroll
        for (int u = 0; u < 8; ++u) acc[u] += bf2f(v[u]);
    }
    short8 o;
#pragma unroll
    for (int u = 0; u < 8; ++u) o[u] = f2bf(acc[u]);
    *(short8*)(zb + b * 64 + g * 8) = o;
}

// ---------------- GEMM2: C = zb(8192xK) * B4t(4096xK)^T + bias --------------
#define BM 128
#define BN 128
#define BK 32

template <int K>
__global__ __launch_bounds__(256) void gemm_bias_kernel(
    const short* __restrict__ A,    // M x K bf16
    const short* __restrict__ Bt,   // N x K bf16
    const float* __restrict__ bias,
    float* __restrict__ C) {
    constexpr int N = 4096;
    __shared__ short As[BM * BK];
    __shared__ short Bs[BN * BK];

    const int tid  = threadIdx.x;
    const int wave = tid >> 6;
    const int lane = tid & 63;

    const int bid = blockIdx.x;
    const int wg  = (bid & 7) * 256 + (bid >> 3);  // 2048 % 8 == 0, bijective
    const int m0 = (wg >> 5) * BM;
    const int n0 = (wg & 31) * BN;

    const int c0i = tid;
    const int c1i = 256 + tid;
    const short* gA0 = A  + (m0 + (c0i >> 2)) * K + ((c0i & 3) << 3);
    const short* gA1 = A  + (m0 + (c1i >> 2)) * K + ((c1i & 3) << 3);
    const short* gB0 = Bt + (n0 + (c0i >> 2)) * K + ((c0i & 3) << 3);
    const short* gB1 = Bt + (n0 + (c1i >> 2)) * K + ((c1i & 3) << 3);
    short* lA0 = As + wave * 512;
    short* lA1 = As + 2048 + wave * 512;
    short* lB0 = Bs + wave * 512;
    short* lB1 = Bs + 2048 + wave * 512;

    const int wr = (wave >> 1) << 6;
    const int wc = (wave & 1) << 6;
    const int r16 = lane & 15;
    const int kq  = (lane >> 4) << 3;

    f32x4 acc[4][4] = {};

    for (int kt = 0; kt < K / BK; ++kt) {
        __builtin_amdgcn_global_load_lds((const __attribute__((address_space(1))) void*)gA0,
                                         (__attribute__((address_space(3))) void*)lA0, 16, 0, 0);
        __builtin_amdgcn_global_load_lds((const __attribute__((address_space(1))) void*)gA1,
                                         (__attribute__((address_space(3))) void*)lA1, 16, 0, 0);
        __builtin_amdgcn_global_load_lds((const __attribute__((address_space(1))) void*)gB0,
                                         (__attribute__((address_space(3))) void*)lB0, 16, 0, 0);
        __builtin_amdgcn_global_load_lds((const __attribute__((address_space(1))) void*)gB1,
                                         (__attribute__((address_space(3))) void*)lB1, 16, 0, 0);
        gA0 += BK; gA1 += BK; gB0 += BK; gB1 += BK;
        __syncthreads();

        short8 a[4], b[4];
#pragma unroll
        for (int f = 0; f < 4; ++f) {
            a[f] = *(const short8*)(As + (wr + f * 16 + r16) * BK + kq);
            b[f] = *(const short8*)(Bs + (wc + f * 16 + r16) * BK + kq);
        }
#pragma unroll
        for (int i = 0; i < 4; ++i)
#pragma unroll
            for (int j = 0; j < 4; ++j)
                acc[i][j] = __builtin_amdgcn_mfma_f32_16x16x32_bf16(
                    a[i], b[j], acc[i][j], 0, 0, 0);
        __syncthreads();
    }

    const int crow = m0 + wr + ((lane >> 4) << 2);
    const int ccol = n0 + wc + r16;
#pragma unroll
    for (int i = 0; i < 4; ++i) {
#pragma unroll
        for (int j = 0; j < 4; ++j) {
            const int r = crow + i * 16;
            const int c = ccol + j * 16;
            const float bz = bias[c];
#pragma unroll
            for (int u = 0; u < 4; ++u)
                C[(r + u) * N + c] = acc[i][j][u] + bz;
        }
    }
}

// ---------------------------------------------------------------------------
extern "C" void kernel_launch(void* const* d_in, const int* in_sizes, int n_in,
                              void* d_out, int out_size, void* d_ws, size_t ws_size,
                              hipStream_t stream) {
    const float* x    = (const float*)d_in[0];
    const float* c0   = (const float*)d_in[1];
    const float* c1   = (const float*)d_in[2];
    const float* c2   = (const float*)d_in[3];
    const float* c3   = (const float*)d_in[4];
    const float* c4   = (const float*)d_in[5];
    const float* c5   = (const float*)d_in[6];
    const float* c6   = (const float*)d_in[7];
    const float* c7   = (const float*)d_in[8];
    const float* bias = (const float*)d_in[9];
    float* out = (float*)d_out;

    char* ws = (char*)d_ws;
    short* zc  = (short*)ws;                       // 8192*512*2 = 8 MiB
    short* zb  = (short*)(ws + (8u << 20));        // 8192*64*2  = 1 MiB
    short* A4t = (short*)(ws + (9u << 20));        // 64*4096*2  = 512 KiB
    short* B4t = (short*)(ws + (9u << 20) + (512u << 10));  // 4096*64*2 = 512 KiB
    float* A3  = (float*)(ws + (10u << 20));       // 512*64*4   = 128 KiB
    float* B5  = A3 + 512 * 64;                    // 64*512*4   = 128 KiB

    tt_chain_small<<<2, 1024, 0, stream>>>(c0, c1, c2, c7, c6, c5, A3, B5);
    tt_chain_wide<<<1536, 256, 0, stream>>>(A3, c3, B5, c4, A4t, B4t);
    gemm1_kernel<<<1024, 256, 0, stream>>>(x, A4t, zc);
    reduce_zc<<<256, 256, 0, stream>>>(zc, zb);
    gemm_bias_kernel<64><<<2048, 256, 0, stream>>>(zb, B4t, bias, out);
}

// Round 4
// 105.531 us; speedup vs baseline: 2.6470x; 2.6470x over previous
//
#include <hip/hip_runtime.h>
#include <hip/hip_bf16.h>

// ---------------------------------------------------------------------------
// TT-linear, rank-64 factorized:
//   W = A4(4096x64) . B4(64x4096)  =>  out = (x_pad @ A4) @ B4 + bias
//   chain : cores -> A4t (64x4096 bf16), B4t (4096x64 bf16)   [many-block]
//   GEMM1 : zb[8192x64] = x @ A4, K split over 8 waves, LDS-reduced in-block
//   GEMM2 : out = zb @ B4t^T + bias, K=64                     (writes 134 MB)
// ---------------------------------------------------------------------------

typedef __attribute__((ext_vector_type(8))) short short8;
typedef __attribute__((ext_vector_type(4))) short s16x4;
typedef __attribute__((ext_vector_type(4))) float f32x4;

__device__ __forceinline__ short f2bf(float f) {
    union { float f; unsigned u; } c; c.f = f;
    unsigned u = c.u;
    unsigned r = (u + 0x7fffu + ((u >> 16) & 1u)) >> 16;  // RNE
    return (short)r;
}

// ---------------- A-side chain step (verified round 1/2) --------------------
// out[(i*8+d)][s] = sum_r in[i][r] * core[(r*8+d)*64 + s]
__global__ void tt_a_step(const float* __restrict__ in,
                          const float* __restrict__ core,
                          float* __restrict__ out) {
    const int row = blockIdx.x;
    const int i = row >> 3, d = row & 7;
    const int s = threadIdx.x;
    float acc = 0.f;
    for (int r = 0; r < 64; ++r)
        acc += in[i * 64 + r] * core[(r * 8 + d) * 64 + s];
    out[row * 64 + s] = acc;
}

// ---------------- B-side chain step (verified round 1/2) --------------------
// out[r][d*Wj + j] = sum_q core[(r*8+d)*64 + q] * in[q*Wj + j]
__global__ void tt_b_step(const float* __restrict__ in,
                          const float* __restrict__ core,
                          float* __restrict__ out, int Wj) {
    const int rd = blockIdx.x;
    const int r = rd >> 3, d = rd & 7;
    for (int j = threadIdx.x; j < Wj; j += 256) {
        float acc = 0.f;
        for (int q = 0; q < 64; ++q)
            acc += core[(r * 8 + d) * 64 + q] * in[q * Wj + j];
        out[r * (8 * Wj) + d * Wj + j] = acc;
    }
}

// ---------------- wide final steps, bf16 transposed outputs (verified r3) ---
// blocks [0,1024):   A4t[s][row] = f2bf( sum_r A3[row>>3][r]*c3[(r*8+d)*64+s] )
// blocks [1024,1536): B4t[(d*512+j)][r] = f2bf( sum_q c4[(r*8+d)*64+q]*B5[q][j] )
__global__ __launch_bounds__(256) void tt_chain_wide(
    const float* __restrict__ A3, const float* __restrict__ c3,
    const float* __restrict__ B5, const float* __restrict__ c4,
    short* __restrict__ A4t, short* __restrict__ B4t) {
    const int bid = blockIdx.x, t = threadIdx.x;
    if (bid < 1024) {
        const int row = (bid << 2) | (t >> 6);
        const int s = t & 63;
        const int i = row >> 3, d = row & 7;
        float acc = 0.f;
        for (int r = 0; r < 64; ++r)
            acc += A3[i * 64 + r] * c3[(r * 8 + d) * 64 + s];
        A4t[s * 4096 + row] = f2bf(acc);
    } else {
        const int rd = bid - 1024;
        const int r = rd >> 3, d = rd & 7;
        for (int j = t; j < 512; j += 256) {
            float acc = 0.f;
            for (int q = 0; q < 64; ++q)
                acc += c4[(r * 8 + d) * 64 + q] * B5[q * 512 + j];
            B4t[(d * 512 + j) * 64 + r] = f2bf(acc);
        }
    }
}

// ---------------- GEMM1 fused: zb = f2bf(x @ A4), in-block split-K ----------
// 512 blocks x 512 threads. Block owns 16 rows; 8 waves split the 125 k-tiles
// (4000 = 125*32, no padding needed); f32 partials reduced through LDS.
__global__ __launch_bounds__(512) void gemm1_fused(
    const float* __restrict__ x, const short* __restrict__ A4t,
    short* __restrict__ zb) {
    __shared__ float zsm[8 * 1024];   // 32 KB: [wave][row(16)][col(64)]
    const int tid = threadIdx.x, wave = tid >> 6, lane = tid & 63;
    const int m0 = blockIdx.x << 4;
    const int r16 = lane & 15, kq = (lane >> 4) << 3;
    const float* xp = x + (long)(m0 + r16) * 4000 + kq;

    f32x4 acc[4] = {};
#pragma unroll 2
    for (int t = wave; t < 125; t += 8) {
        const int k0 = t << 5;
        f32x4 u0 = *(const f32x4*)(xp + k0);
        f32x4 u1 = *(const f32x4*)(xp + k0 + 4);
        short8 a;
        a[0] = f2bf(u0[0]); a[1] = f2bf(u0[1]);
        a[2] = f2bf(u0[2]); a[3] = f2bf(u0[3]);
        a[4] = f2bf(u1[0]); a[5] = f2bf(u1[1]);
        a[6] = f2bf(u1[2]); a[7] = f2bf(u1[3]);
#pragma unroll
        for (int f = 0; f < 4; ++f) {
            short8 b = *(const short8*)(A4t + (f * 16 + r16) * 4096 + k0 + kq);
            acc[f] = __builtin_amdgcn_mfma_f32_16x16x32_bf16(a, b, acc[f], 0, 0, 0);
        }
    }
    // C/D layout: col = f*16 + (lane&15), row = (lane>>4)*4 + u
    const int prow = (lane >> 4) << 2;
#pragma unroll
    for (int f = 0; f < 4; ++f)
#pragma unroll
        for (int u = 0; u < 4; ++u)
            zsm[wave * 1024 + (prow + u) * 64 + f * 16 + r16] = acc[f][u];
    __syncthreads();
    if (tid < 256) {
        const f32x4* zp = (const f32x4*)zsm;  // 256 f32x4 per wave-slab
        f32x4 s = zp[tid];
#pragma unroll
        for (int w = 1; w < 8; ++w) s += zp[w * 256 + tid];
        s16x4 o;
#pragma unroll
        for (int u = 0; u < 4; ++u) o[u] = f2bf(s[u]);
        const int orow = tid >> 4, ocol = (tid & 15) << 2;
        *(s16x4*)(zb + (m0 + orow) * 64 + ocol) = o;
    }
}

// ---------------- GEMM2: C = zb(8192xK) * B4t(4096xK)^T + bias --------------
#define BM 128
#define BN 128
#define BK 32

template <int K>
__global__ __launch_bounds__(256) void gemm_bias_kernel(
    const short* __restrict__ A,    // M x K bf16
    const short* __restrict__ Bt,   // N x K bf16
    const float* __restrict__ bias,
    float* __restrict__ C) {
    constexpr int N = 4096;
    __shared__ short As[BM * BK];
    __shared__ short Bs[BN * BK];

    const int tid  = threadIdx.x;
    const int wave = tid >> 6;
    const int lane = tid & 63;

    const int bid = blockIdx.x;
    const int wg  = (bid & 7) * 256 + (bid >> 3);  // 2048 % 8 == 0, bijective
    const int m0 = (wg >> 5) * BM;
    const int n0 = (wg & 31) * BN;

    const int c0i = tid;
    const int c1i = 256 + tid;
    const short* gA0 = A  + (m0 + (c0i >> 2)) * K + ((c0i & 3) << 3);
    const short* gA1 = A  + (m0 + (c1i >> 2)) * K + ((c1i & 3) << 3);
    const short* gB0 = Bt + (n0 + (c0i >> 2)) * K + ((c0i & 3) << 3);
    const short* gB1 = Bt + (n0 + (c1i >> 2)) * K + ((c1i & 3) << 3);
    short* lA0 = As + wave * 512;
    short* lA1 = As + 2048 + wave * 512;
    short* lB0 = Bs + wave * 512;
    short* lB1 = Bs + 2048 + wave * 512;

    const int wr = (wave >> 1) << 6;
    const int wc = (wave & 1) << 6;
    const int r16 = lane & 15;
    const int kq  = (lane >> 4) << 3;

    f32x4 acc[4][4] = {};

    for (int kt = 0; kt < K / BK; ++kt) {
        __builtin_amdgcn_global_load_lds((const __attribute__((address_space(1))) void*)gA0,
                                         (__attribute__((address_space(3))) void*)lA0, 16, 0, 0);
        __builtin_amdgcn_global_load_lds((const __attribute__((address_space(1))) void*)gA1,
                                         (__attribute__((address_space(3))) void*)lA1, 16, 0, 0);
        __builtin_amdgcn_global_load_lds((const __attribute__((address_space(1))) void*)gB0,
                                         (__attribute__((address_space(3))) void*)lB0, 16, 0, 0);
        __builtin_amdgcn_global_load_lds((const __attribute__((address_space(1))) void*)gB1,
                                         (__attribute__((address_space(3))) void*)lB1, 16, 0, 0);
        gA0 += BK; gA1 += BK; gB0 += BK; gB1 += BK;
        __syncthreads();

        short8 a[4], b[4];
#pragma unroll
        for (int f = 0; f < 4; ++f) {
            a[f] = *(const short8*)(As + (wr + f * 16 + r16) * BK + kq);
            b[f] = *(const short8*)(Bs + (wc + f * 16 + r16) * BK + kq);
        }
#pragma unroll
        for (int i = 0; i < 4; ++i)
#pragma unroll
            for (int j = 0; j < 4; ++j)
                acc[i][j] = __builtin_amdgcn_mfma_f32_16x16x32_bf16(
                    a[i], b[j], acc[i][j], 0, 0, 0);
        __syncthreads();
    }

    const int crow = m0 + wr + ((lane >> 4) << 2);
    const int ccol = n0 + wc + r16;
#pragma unroll
    for (int i = 0; i < 4; ++i) {
#pragma unroll
        for (int j = 0; j < 4; ++j) {
            const int r = crow + i * 16;
            const int c = ccol + j * 16;
            const float bz = bias[c];
#pragma unroll
            for (int u = 0; u < 4; ++u)
                C[(r + u) * N + c] = acc[i][j][u] + bz;
        }
    }
}

// ---------------------------------------------------------------------------
extern "C" void kernel_launch(void* const* d_in, const int* in_sizes, int n_in,
                              void* d_out, int out_size, void* d_ws, size_t ws_size,
                              hipStream_t stream) {
    const float* x    = (const float*)d_in[0];
    const float* c0   = (const float*)d_in[1];
    const float* c1   = (const float*)d_in[2];
    const float* c2   = (const float*)d_in[3];
    const float* c3   = (const float*)d_in[4];
    const float* c4   = (const float*)d_in[5];
    const float* c5   = (const float*)d_in[6];
    const float* c6   = (const float*)d_in[7];
    const float* c7   = (const float*)d_in[8];
    const float* bias = (const float*)d_in[9];
    float* out = (float*)d_out;

    char* ws = (char*)d_ws;
    short* zb  = (short*)ws;                              // 8192*64*2 = 1 MiB
    short* A4t = (short*)(ws + (1u << 20));               // 64*4096*2 = 512 KiB
    short* B4t = (short*)(ws + (1u << 20) + (512u << 10)); // 4096*64*2 = 512 KiB
    float* A2  = (float*)(ws + (2u << 20));               // 64*64
    float* A3  = A2 + 64 * 64;                            // 512*64
    float* B6  = A3 + 512 * 64;                           // 64*64
    float* B5  = B6 + 64 * 64;                            // 64*512

    tt_a_step<<<64, 64, 0, stream>>>(c0, c1, A2);         // (8,64)  -> (64,64)
    tt_a_step<<<512, 64, 0, stream>>>(A2, c2, A3);        // (64,64) -> (512,64)
    tt_b_step<<<512, 256, 0, stream>>>(c7, c6, B6, 8);    // (64,8)  -> (64,64)
    tt_b_step<<<512, 256, 0, stream>>>(B6, c5, B5, 64);   // (64,64) -> (64,512)
    tt_chain_wide<<<1536, 256, 0, stream>>>(A3, c3, B5, c4, A4t, B4t);

    gemm1_fused<<<512, 512, 0, stream>>>(x, A4t, zb);
    gemm_bias_kernel<64><<<2048, 256, 0, stream>>>(zb, B4t, bias, out);
}